// Round 1
// baseline (389.173 us; speedup 1.0000x reference)
//
#include <hip/hip_runtime.h>

#define RES 256
#define THRESH 0.01f

__device__ __forceinline__ int voxel_coord(float p) {
    // Replicate reference rounding exactly:
    // pts = -1 + p*2 ; coord = ((pts+1)/2)*256 ; trunc ; clamp
    float a = -1.0f + p * 2.0f;          // rounds once (mul by 2 exact)
    float c = ((a + 1.0f) * 0.5f) * 256.0f;  // rounds once at (a+1); scalings exact
    int v = (int)c;                      // truncation (c >= 0)
    v = v < 0 ? 0 : v;
    v = v > (RES - 1) ? (RES - 1) : v;
    return v;
}

__global__ void occ_scatter_kernel(const float4* __restrict__ pts4,
                                   const float4* __restrict__ dens4,
                                   float* __restrict__ grid, int n4) {
    int t = blockIdx.x * blockDim.x + threadIdx.x;
    int stride = gridDim.x * blockDim.x;
    for (int i = t; i < n4; i += stride) {
        // 4 points = 12 floats = 3 float4 loads (fully coalesced, 16B/lane)
        float4 p0 = pts4[3 * i + 0];
        float4 p1 = pts4[3 * i + 1];
        float4 p2 = pts4[3 * i + 2];
        float4 d  = dens4[i];

        float px[4] = {p0.x, p0.w, p1.z, p2.y};
        float py[4] = {p0.y, p1.x, p1.w, p2.z};
        float pz[4] = {p0.z, p1.y, p2.x, p2.w};
        float dd[4] = {d.x, d.y, d.z, d.w};

        #pragma unroll
        for (int k = 0; k < 4; ++k) {
            if (dd[k] > THRESH) {
                int ix = voxel_coord(px[k]);
                int iy = voxel_coord(py[k]);
                int iz = voxel_coord(pz[k]);
                // identical value stored by all writers -> plain store is safe
                grid[((ix * RES) + iy) * RES + iz] = 1.0f;
            }
        }
    }
}

extern "C" void kernel_launch(void* const* d_in, const int* in_sizes, int n_in,
                              void* d_out, int out_size, void* d_ws, size_t ws_size,
                              hipStream_t stream) {
    const float* points    = (const float*)d_in[0];   // [N,3]
    const float* densities = (const float*)d_in[1];   // [N]
    float* grid = (float*)d_out;                      // 256^3 floats

    int n = in_sizes[1];          // N = 16,000,000 (divisible by 4)
    int n4 = n / 4;

    // d_out is poisoned to 0xAA by the harness; zero it (async, capture-safe)
    hipMemsetAsync(d_out, 0, (size_t)out_size * sizeof(float), stream);

    int block = 256;
    int blocks = 2048;            // grid-stride; ~8 iters/thread at N=16M
    occ_scatter_kernel<<<blocks, block, 0, stream>>>(
        (const float4*)points, (const float4*)densities, grid, n4);
}

// Round 3
// 299.552 us; speedup vs baseline: 1.2992x; 1.2992x over previous
//
#include <hip/hip_runtime.h>

#define RES 256
#define THRESH 0.01f
#define GRID_VOX (RES * RES * RES)   // 16,777,216

typedef float vf4 __attribute__((ext_vector_type(4)));  // builtin-compatible

__device__ __forceinline__ int voxel_coord(float p) {
    // Replicate reference rounding exactly:
    // pts = -1 + p*2 ; coord = ((pts+1)/2)*256 ; trunc ; clamp
    float a = -1.0f + p * 2.0f;              // mul by 2 exact; one rounding
    float c = ((a + 1.0f) * 0.5f) * 256.0f;  // one rounding at (a+1); scalings exact
    int v = (int)c;
    v = v < 0 ? 0 : v;
    v = v > (RES - 1) ? (RES - 1) : v;
    return v;
}

// Phase 1: scatter 1-byte flags into a 16 MB byte grid (fits L2 4x better
// than the 64 MB float grid). All writers store the same value -> race-free.
__global__ void occ_scatter_bytes(const vf4* __restrict__ pts4,
                                  const vf4* __restrict__ dens4,
                                  unsigned char* __restrict__ bgrid, int n4) {
    int t = blockIdx.x * blockDim.x + threadIdx.x;
    int stride = gridDim.x * blockDim.x;
    for (int i = t; i < n4; i += stride) {
        // streaming inputs: non-temporal so they don't evict hot grid lines
        vf4 p0 = __builtin_nontemporal_load(&pts4[3 * i + 0]);
        vf4 p1 = __builtin_nontemporal_load(&pts4[3 * i + 1]);
        vf4 p2 = __builtin_nontemporal_load(&pts4[3 * i + 2]);
        vf4 d  = __builtin_nontemporal_load(&dens4[i]);

        float px[4] = {p0.x, p0.w, p1.z, p2.y};
        float py[4] = {p0.y, p1.x, p1.w, p2.z};
        float pz[4] = {p0.z, p1.y, p2.x, p2.w};
        float dd[4] = {d.x, d.y, d.z, d.w};

        #pragma unroll
        for (int k = 0; k < 4; ++k) {
            if (dd[k] > THRESH) {
                int ix = voxel_coord(px[k]);
                int iy = voxel_coord(py[k]);
                int iz = voxel_coord(pz[k]);
                bgrid[((ix << 8) | iy) * RES + iz] = (unsigned char)1;
            }
        }
    }
}

// Phase 2: bytes -> floats, fully coalesced. Also performs the zero-init of
// d_out (writes 0.0f where byte==0), so no 64 MB memset is needed.
__global__ void occ_expand(const uint4* __restrict__ bgrid16,
                           float4* __restrict__ grid4) {
    int i = blockIdx.x * blockDim.x + threadIdx.x;  // one thread = 16 voxels
    uint4 w = bgrid16[i];
    unsigned int ws[4] = {w.x, w.y, w.z, w.w};
    #pragma unroll
    for (int q = 0; q < 4; ++q) {
        unsigned int v = ws[q];
        float4 f;
        f.x = (v & 0x000000FFu) ? 1.0f : 0.0f;
        f.y = (v & 0x0000FF00u) ? 1.0f : 0.0f;
        f.z = (v & 0x00FF0000u) ? 1.0f : 0.0f;
        f.w = (v & 0xFF000000u) ? 1.0f : 0.0f;
        grid4[i * 4 + q] = f;
    }
}

// Fallback (ws too small): direct float scatter as in round 1.
__global__ void occ_scatter_float(const float4* __restrict__ pts4,
                                  const float4* __restrict__ dens4,
                                  float* __restrict__ grid, int n4) {
    int t = blockIdx.x * blockDim.x + threadIdx.x;
    int stride = gridDim.x * blockDim.x;
    for (int i = t; i < n4; i += stride) {
        float4 p0 = pts4[3 * i + 0];
        float4 p1 = pts4[3 * i + 1];
        float4 p2 = pts4[3 * i + 2];
        float4 d  = dens4[i];
        float px[4] = {p0.x, p0.w, p1.z, p2.y};
        float py[4] = {p0.y, p1.x, p1.w, p2.z};
        float pz[4] = {p0.z, p1.y, p2.x, p2.w};
        float dd[4] = {d.x, d.y, d.z, d.w};
        #pragma unroll
        for (int k = 0; k < 4; ++k) {
            if (dd[k] > THRESH) {
                int ix = voxel_coord(px[k]);
                int iy = voxel_coord(py[k]);
                int iz = voxel_coord(pz[k]);
                grid[((ix * RES) + iy) * RES + iz] = 1.0f;
            }
        }
    }
}

extern "C" void kernel_launch(void* const* d_in, const int* in_sizes, int n_in,
                              void* d_out, int out_size, void* d_ws, size_t ws_size,
                              hipStream_t stream) {
    const float* points    = (const float*)d_in[0];   // [N,3]
    const float* densities = (const float*)d_in[1];   // [N]
    float* grid = (float*)d_out;                      // 256^3 floats

    int n  = in_sizes[1];     // 16,000,000 (divisible by 4)
    int n4 = n / 4;

    if (ws_size >= (size_t)GRID_VOX) {
        unsigned char* bgrid = (unsigned char*)d_ws;
        // zero the 16 MB byte grid (4x cheaper than zeroing d_out)
        (void)hipMemsetAsync(d_ws, 0, (size_t)GRID_VOX, stream);

        occ_scatter_bytes<<<2048, 256, 0, stream>>>(
            (const vf4*)points, (const vf4*)densities, bgrid, n4);

        // 16,777,216 voxels / 16 per thread = 1,048,576 threads
        occ_expand<<<GRID_VOX / (16 * 256), 256, 0, stream>>>(
            (const uint4*)bgrid, (float4*)grid);
    } else {
        (void)hipMemsetAsync(d_out, 0, (size_t)out_size * sizeof(float), stream);
        occ_scatter_float<<<2048, 256, 0, stream>>>(
            (const float4*)points, (const float4*)densities, grid, n4);
    }
}